// Round 2
// baseline (174.620 us; speedup 1.0000x reference)
//
#include <hip/hip_runtime.h>
#include <stdint.h>

#define HWPOS 1024
#define CCH   256
#define RROWS 128   // 2B
#define EPSF  1.1920928955078125e-07f

typedef __attribute__((ext_vector_type(4))) float float4v;

__device__ __forceinline__ uint32_t pk4_fp8(float a, float b, float c, float d) {
  int v = 0;
  v = __builtin_amdgcn_cvt_pk_fp8_f32(a, b, v, false);  // bytes 0,1
  v = __builtin_amdgcn_cvt_pk_fp8_f32(c, d, v, true);   // bytes 2,3
  return (uint32_t)v;
}

// ws layout (fp8 bytes): addr(hw,r,s) = hw*32768 + r*256 + s*16  (+0..15)
//   s = swizzled 16B chunk slot: data chunk dd (c = dd*16..+15) stored at
//   slot s = dd ^ (r & 15)  -> conflict-free LDS b64 fragment reads in gram.

// ---------------------------------------------------------------------------
// Kernel 1 (v8, fp8): transpose [B,C,H,W] f32 -> ws fp8-e4m3 (layout above).
// Block = 2 rows x 32 hw x 256 c, LDS-free. Lane: 16 float4 loads (16 c at
// 1KB stride, 4 hw each); per wave-instruction: 8 FULL 128B read granules.
// Stores: per (hw,q) 8 lanes write 8 swizzle-permuted 16B chunks covering an
// aligned 128B half-row -> full write granules. Also zeroes out[0] (block 0).
// v8 change: __launch_bounds__(256, 4) -> 128-VGPR budget so all 16 float4
// loads stay in flight (v7's 36-VGPR allocation serialized them into ~4
// batches, one HBM latency each -> 54 us latency-bound, 3% VALUBusy).
// ---------------------------------------------------------------------------
__global__ __launch_bounds__(256, 4) void k_transpose(const float* __restrict__ inp,
                                                      const float* __restrict__ tgt,
                                                      unsigned char* __restrict__ wsF,
                                                      float* __restrict__ out) {
  const int t    = threadIdx.x;
  const int hq   = t & 7;           // hw quad (4 hw)
  const int dd   = (t >> 3) & 15;   // c-chunk (16 c)
  const int rsel = t >> 7;          // 0..1
  const int r    = blockIdx.y * 2 + rsel;
  const int hw0  = blockIdx.x * 32;
  if (blockIdx.x == 0 && blockIdx.y == 0 && t == 0) out[0] = 0.0f;
  const int m = r & 15;
  const int s = dd ^ m;             // swizzled chunk slot
  const float* src = (r < 64) ? (inp + (size_t)r * CCH * HWPOS)
                              : (tgt + (size_t)(r - 64) * CCH * HWPOS);
  const float* p = src + (size_t)(dd * 16) * HWPOS + hw0 + hq * 4;
  float4 v[16];
#pragma unroll
  for (int e = 0; e < 16; ++e) v[e] = *(const float4*)(p + (size_t)e * HWPOS);
#pragma unroll
  for (int q = 0; q < 4; ++q) {
    float x[16];
#pragma unroll
    for (int e = 0; e < 16; ++e)
      x[e] = (q == 0) ? v[e].x : (q == 1) ? v[e].y : (q == 2) ? v[e].z : v[e].w;
    uint4 o;
    o.x = pk4_fp8(x[0],  x[1],  x[2],  x[3]);
    o.y = pk4_fp8(x[4],  x[5],  x[6],  x[7]);
    o.z = pk4_fp8(x[8],  x[9],  x[10], x[11]);
    o.w = pk4_fp8(x[12], x[13], x[14], x[15]);
    const size_t a = (size_t)(hw0 + hq * 4 + q) * 32768 + (size_t)r * 256 + s * 16;
    *(uint4*)(wsF + a) = o;
  }
}

// ---------------------------------------------------------------------------
// Kernel 2 (v5, fp8): one block per hw. Whole 32KB fp8 image in ONE LDS
// buffer (single barrier, no K-split pipeline). 8 waves; wave w owns row-tile
// w x 8 col-tiles via mfma_f32_16x16x32_fp8_fp8 (b64 frags). Norms from the
// gram diagonal; fused masked log-softmax + positive-pair extraction; one
// atomicAdd per block. Scratch-free (no dynamic register indexing).
// ---------------------------------------------------------------------------
__global__ __launch_bounds__(512, 4) void k_gram(const unsigned char* __restrict__ wsF,
                                                 float* __restrict__ out) {
  __shared__ unsigned char Fs[32768];   // full fp8 image, swizzled
  __shared__ float sInv[RROWS];
  __shared__ float wred[8];
  const int t  = threadIdx.x;
  const int hw = blockIdx.x;
  const int lane = t & 63;
  const int w    = t >> 6;        // wave id 0..7 = row-tile
  const int lid  = lane & 15;
  const int quad = lane >> 4;
  float4v acc[8];
#pragma unroll
  for (int ni = 0; ni < 8; ++ni) acc[ni] = (float4v){0.f, 0.f, 0.f, 0.f};
  const unsigned char* gsrc = wsF + (size_t)hw * 32768;
#pragma unroll
  for (int it = 0; it < 4; ++it) {
    const size_t ch = (size_t)it * 512 + t;
    __builtin_amdgcn_global_load_lds(
        (const __attribute__((address_space(1))) unsigned int*)(gsrc + ch * 16),
        (__attribute__((address_space(3))) unsigned int*)(Fs + ch * 16),
        16, 0, 0);
  }
  __syncthreads();
  const int rowA = (w << 4) | lid;
#pragma unroll
  for (int ks = 0; ks < 8; ++ks) {
    const int d    = 2 * ks + (quad >> 1);      // data chunk for this frag
    const int off  = ((d ^ lid) << 4) + (quad & 1) * 8;  // swizzled byte off
    long a = *(const long*)&Fs[rowA * 256 + off];
#pragma unroll
    for (int ni = 0; ni < 8; ++ni) {
      long b = *(const long*)&Fs[(((ni << 4) | lid)) * 256 + off];
      acc[ni] = __builtin_amdgcn_mfma_f32_16x16x32_fp8_fp8(a, b, acc[ni], 0, 0, 0);
    }
  }
  // diagonal extract (no dynamic indexing): tile w (uniform), elem lid&3
  {
    float diagv = 0.f;
#pragma unroll
    for (int ni = 0; ni < 8; ++ni) {
      if (ni == w) {
#pragma unroll
        for (int e = 0; e < 4; ++e)
          if (e == (lid & 3)) diagv = acc[ni][e];
      }
    }
    if ((lid >> 2) == quad) {
      sInv[(w << 4) | lid] = 1.0f / fmaxf(sqrtf(diagv), EPSF);
    }
  }
  __syncthreads();
  float invj[8];
#pragma unroll
  for (int ni = 0; ni < 8; ++ni) invj[ni] = sInv[(ni << 4) | lid];
  const int tj = (w + 4) & 7;     // partner col-tile (wave-uniform)
  float lacc = 0.f;
#pragma unroll
  for (int reg = 0; reg < 4; ++reg) {
    const int rloc = quad * 4 + reg;           // local row in tile
    const int rg   = (w << 4) | rloc;          // global row 0..127
    const float invi = sInv[rg];
    float v[8];
#pragma unroll
    for (int ni = 0; ni < 8; ++ni) v[ni] = 2.0f * acc[ni][reg] * invi * invj[ni];
#pragma unroll
    for (int ni = 0; ni < 8; ++ni)
      if (ni == w && lid == rloc) v[ni] = -3.0e38f;   // mask diagonal
    float mx = v[0];
#pragma unroll
    for (int ni = 1; ni < 8; ++ni) mx = fmaxf(mx, v[ni]);
#pragma unroll
    for (int sh = 1; sh < 16; sh <<= 1) mx = fmaxf(mx, __shfl_xor(mx, sh, 16));
    float sm = 0.f;
#pragma unroll
    for (int ni = 0; ni < 8; ++ni) sm += __expf(v[ni] - mx);
#pragma unroll
    for (int sh = 1; sh < 16; sh <<= 1) sm += __shfl_xor(sm, sh, 16);
    const float lse = mx + __logf(sm);
    float cand = 0.f;
#pragma unroll
    for (int ni = 0; ni < 8; ++ni)
      if (ni == tj) cand = v[ni];                // positive-pair tile (uniform)
    const float vp = __shfl(cand, rloc, 16);
    lacc += vp - lse;                            // x16 lanes per row
  }
#pragma unroll
  for (int sh = 1; sh < 64; sh <<= 1) lacc += __shfl_xor(lacc, sh, 64);
  if (lane == 0) wred[w] = lacc;
  __syncthreads();
  if (t == 0) {
    float tot = 0.f;
#pragma unroll
    for (int i = 0; i < 8; ++i) tot += wred[i];
    // tot = 16 * sum_rows(pos) for this hw; loss = -sum/(HW*2B) with x16 dup
    atomicAdd(out, -tot * (1.0f / 2097152.0f));
  }
}

extern "C" void kernel_launch(void* const* d_in, const int* in_sizes, int n_in,
                              void* d_out, int out_size, void* d_ws, size_t ws_size,
                              hipStream_t stream) {
  const float* inp = (const float*)d_in[0];
  const float* tgt = (const float*)d_in[1];
  unsigned char* wsF = (unsigned char*)d_ws;
  k_transpose<<<dim3(32, 64), 256, 0, stream>>>(inp, tgt, wsF, (float*)d_out);
  k_gram<<<dim3(HWPOS), 512, 0, stream>>>(wsF, (float*)d_out);
}

// Round 3
// 174.343 us; speedup vs baseline: 1.0016x; 1.0016x over previous
//
#include <hip/hip_runtime.h>
#include <stdint.h>

#define HWPOS 1024
#define CCH   256
#define RROWS 128   // 2B
#define EPSF  1.1920928955078125e-07f

typedef __attribute__((ext_vector_type(4))) float float4v;

__device__ __forceinline__ uint32_t pk4_fp8(float a, float b, float c, float d) {
  int v = 0;
  v = __builtin_amdgcn_cvt_pk_fp8_f32(a, b, v, false);  // bytes 0,1
  v = __builtin_amdgcn_cvt_pk_fp8_f32(c, d, v, true);   // bytes 2,3
  return (uint32_t)v;
}

// ws layout (fp8 bytes): addr(hw,r,s) = hw*32768 + r*256 + s*16  (+0..15)
//   s = swizzled 16B chunk slot: data chunk dd (c = dd*16..+15) stored at
//   slot s = dd ^ (r & 15)  -> conflict-free LDS b64 fragment reads in gram.

// ---------------------------------------------------------------------------
// Kernel 1 (v9, fp8): transpose [B,C,H,W] f32 -> ws fp8-e4m3 (layout above).
// Block = 2 rows x 32 hw x 256 c, LDS-free. Lane: 16 float4 loads (16 c at
// 1KB stride, 4 hw each); per wave-instruction: 8 FULL 128B read granules.
// Stores: per (hw,q) 8 lanes write 8 swizzle-permuted 16B chunks covering an
// aligned 128B half-row -> full write granules. Also zeroes out[0] (block 0).
// v9 change: sched_barrier(0) after the load loop. v8's launch_bounds alone
// left VGPR=36 -- the compiler legally split into 4 {load4, drain, cvt}
// batches (o.x needs only v[0..3] etc.), i.e. 4 serialized memory round
// trips per wave. The barrier forces all 16 loads issued before any cvt
// (one latency exposure, descending vmcnt drain). 128-VGPR budget kept.
// ---------------------------------------------------------------------------
__global__ __launch_bounds__(256, 4) void k_transpose(const float* __restrict__ inp,
                                                      const float* __restrict__ tgt,
                                                      unsigned char* __restrict__ wsF,
                                                      float* __restrict__ out) {
  const int t    = threadIdx.x;
  const int hq   = t & 7;           // hw quad (4 hw)
  const int dd   = (t >> 3) & 15;   // c-chunk (16 c)
  const int rsel = t >> 7;          // 0..1
  const int r    = blockIdx.y * 2 + rsel;
  const int hw0  = blockIdx.x * 32;
  if (blockIdx.x == 0 && blockIdx.y == 0 && t == 0) out[0] = 0.0f;
  const int m = r & 15;
  const int s = dd ^ m;             // swizzled chunk slot
  const float* src = (r < 64) ? (inp + (size_t)r * CCH * HWPOS)
                              : (tgt + (size_t)(r - 64) * CCH * HWPOS);
  const float* p = src + (size_t)(dd * 16) * HWPOS + hw0 + hq * 4;
  float4 v[16];
#pragma unroll
  for (int e = 0; e < 16; ++e) v[e] = *(const float4*)(p + (size_t)e * HWPOS);
  __builtin_amdgcn_sched_barrier(0);   // all 16 loads in flight before any cvt
#pragma unroll
  for (int q = 0; q < 4; ++q) {
    float x[16];
#pragma unroll
    for (int e = 0; e < 16; ++e)
      x[e] = (q == 0) ? v[e].x : (q == 1) ? v[e].y : (q == 2) ? v[e].z : v[e].w;
    uint4 o;
    o.x = pk4_fp8(x[0],  x[1],  x[2],  x[3]);
    o.y = pk4_fp8(x[4],  x[5],  x[6],  x[7]);
    o.z = pk4_fp8(x[8],  x[9],  x[10], x[11]);
    o.w = pk4_fp8(x[12], x[13], x[14], x[15]);
    const size_t a = (size_t)(hw0 + hq * 4 + q) * 32768 + (size_t)r * 256 + s * 16;
    *(uint4*)(wsF + a) = o;
  }
}

// ---------------------------------------------------------------------------
// Kernel 2 (v5, fp8): one block per hw. Whole 32KB fp8 image in ONE LDS
// buffer (single barrier, no K-split pipeline). 8 waves; wave w owns row-tile
// w x 8 col-tiles via mfma_f32_16x16x32_fp8_fp8 (b64 frags). Norms from the
// gram diagonal; fused masked log-softmax + positive-pair extraction; one
// atomicAdd per block. Scratch-free (no dynamic register indexing).
// ---------------------------------------------------------------------------
__global__ __launch_bounds__(512, 4) void k_gram(const unsigned char* __restrict__ wsF,
                                                 float* __restrict__ out) {
  __shared__ unsigned char Fs[32768];   // full fp8 image, swizzled
  __shared__ float sInv[RROWS];
  __shared__ float wred[8];
  const int t  = threadIdx.x;
  const int hw = blockIdx.x;
  const int lane = t & 63;
  const int w    = t >> 6;        // wave id 0..7 = row-tile
  const int lid  = lane & 15;
  const int quad = lane >> 4;
  float4v acc[8];
#pragma unroll
  for (int ni = 0; ni < 8; ++ni) acc[ni] = (float4v){0.f, 0.f, 0.f, 0.f};
  const unsigned char* gsrc = wsF + (size_t)hw * 32768;
#pragma unroll
  for (int it = 0; it < 4; ++it) {
    const size_t ch = (size_t)it * 512 + t;
    __builtin_amdgcn_global_load_lds(
        (const __attribute__((address_space(1))) unsigned int*)(gsrc + ch * 16),
        (__attribute__((address_space(3))) unsigned int*)(Fs + ch * 16),
        16, 0, 0);
  }
  __syncthreads();
  const int rowA = (w << 4) | lid;
#pragma unroll
  for (int ks = 0; ks < 8; ++ks) {
    const int d    = 2 * ks + (quad >> 1);      // data chunk for this frag
    const int off  = ((d ^ lid) << 4) + (quad & 1) * 8;  // swizzled byte off
    long a = *(const long*)&Fs[rowA * 256 + off];
#pragma unroll
    for (int ni = 0; ni < 8; ++ni) {
      long b = *(const long*)&Fs[(((ni << 4) | lid)) * 256 + off];
      acc[ni] = __builtin_amdgcn_mfma_f32_16x16x32_fp8_fp8(a, b, acc[ni], 0, 0, 0);
    }
  }
  // diagonal extract (no dynamic indexing): tile w (uniform), elem lid&3
  {
    float diagv = 0.f;
#pragma unroll
    for (int ni = 0; ni < 8; ++ni) {
      if (ni == w) {
#pragma unroll
        for (int e = 0; e < 4; ++e)
          if (e == (lid & 3)) diagv = acc[ni][e];
      }
    }
    if ((lid >> 2) == quad) {
      sInv[(w << 4) | lid] = 1.0f / fmaxf(sqrtf(diagv), EPSF);
    }
  }
  __syncthreads();
  float invj[8];
#pragma unroll
  for (int ni = 0; ni < 8; ++ni) invj[ni] = sInv[(ni << 4) | lid];
  const int tj = (w + 4) & 7;     // partner col-tile (wave-uniform)
  float lacc = 0.f;
#pragma unroll
  for (int reg = 0; reg < 4; ++reg) {
    const int rloc = quad * 4 + reg;           // local row in tile
    const int rg   = (w << 4) | rloc;          // global row 0..127
    const float invi = sInv[rg];
    float v[8];
#pragma unroll
    for (int ni = 0; ni < 8; ++ni) v[ni] = 2.0f * acc[ni][reg] * invi * invj[ni];
#pragma unroll
    for (int ni = 0; ni < 8; ++ni)
      if (ni == w && lid == rloc) v[ni] = -3.0e38f;   // mask diagonal
    float mx = v[0];
#pragma unroll
    for (int ni = 1; ni < 8; ++ni) mx = fmaxf(mx, v[ni]);
#pragma unroll
    for (int sh = 1; sh < 16; sh <<= 1) mx = fmaxf(mx, __shfl_xor(mx, sh, 16));
    float sm = 0.f;
#pragma unroll
    for (int ni = 0; ni < 8; ++ni) sm += __expf(v[ni] - mx);
#pragma unroll
    for (int sh = 1; sh < 16; sh <<= 1) sm += __shfl_xor(sm, sh, 16);
    const float lse = mx + __logf(sm);
    float cand = 0.f;
#pragma unroll
    for (int ni = 0; ni < 8; ++ni)
      if (ni == tj) cand = v[ni];                // positive-pair tile (uniform)
    const float vp = __shfl(cand, rloc, 16);
    lacc += vp - lse;                            // x16 lanes per row
  }
#pragma unroll
  for (int sh = 1; sh < 64; sh <<= 1) lacc += __shfl_xor(lacc, sh, 64);
  if (lane == 0) wred[w] = lacc;
  __syncthreads();
  if (t == 0) {
    float tot = 0.f;
#pragma unroll
    for (int i = 0; i < 8; ++i) tot += wred[i];
    // tot = 16 * sum_rows(pos) for this hw; loss = -sum/(HW*2B) with x16 dup
    atomicAdd(out, -tot * (1.0f / 2097152.0f));
  }
}

extern "C" void kernel_launch(void* const* d_in, const int* in_sizes, int n_in,
                              void* d_out, int out_size, void* d_ws, size_t ws_size,
                              hipStream_t stream) {
  const float* inp = (const float*)d_in[0];
  const float* tgt = (const float*)d_in[1];
  unsigned char* wsF = (unsigned char*)d_ws;
  k_transpose<<<dim3(32, 64), 256, 0, stream>>>(inp, tgt, wsF, (float*)d_out);
  k_gram<<<dim3(HWPOS), 512, 0, stream>>>(wsF, (float*)d_out);
}